// Round 1
// 510.297 us; speedup vs baseline: 1.2707x; 1.2707x over previous
//
#include <hip/hip_runtime.h>
#include <hip/hip_bf16.h>
#include <stdint.h>

// ---------------------------------------------------------------------------
// Int8Linear: y = x @ Wq^T + b, Wq = dequant(int8-quant(W)) per-tensor absmax.
// R5: GEMM rewritten as the 256x256 / BK=64 / 8-wave 8-phase pipeline
//     (counted vmcnt(6), raw s_barrier, setprio around MFMA, (row&7) XOR
//     LDS swizzle applied via pre-swizzled global_load_lds source, XCD-aware
//     block swizzle).  Pre-pass (partial_max + quantcast) unchanged from R4.
// Workspace: [0..2KB) partial maxima | 4096 + x_bf16 (64MiB) | wq_bf16 (32MiB)
// ---------------------------------------------------------------------------

typedef __attribute__((ext_vector_type(8))) short short8;    // 8 x bf16
typedef __attribute__((ext_vector_type(4))) float f32x4;     // 16x16 acc

#define BM 256
#define BN 256
#define BK 64
#define PMAX_BLOCKS 512

// float -> bf16, round-to-nearest-even
__device__ __forceinline__ unsigned short f2bf(float f) {
    unsigned u = __float_as_uint(f);
    unsigned r = 0x7fffu + ((u >> 16) & 1u);
    return (unsigned short)((u + r) >> 16);
}

// ---------------- per-block partial absmax over W --------------------------
__global__ void partial_max_kernel(const float* __restrict__ W,
                                   float* __restrict__ partials, int n4) {
    int i0 = blockIdx.x * blockDim.x + threadIdx.x;
    int stride = gridDim.x * blockDim.x;
    float m = 0.f;
    for (int idx = i0; idx < n4; idx += stride) {
        float4 v = ((const float4*)W)[idx];
        m = fmaxf(m, fmaxf(fmaxf(fabsf(v.x), fabsf(v.y)),
                           fmaxf(fabsf(v.z), fabsf(v.w))));
    }
    #pragma unroll
    for (int off = 32; off > 0; off >>= 1)
        m = fmaxf(m, __shfl_down(m, off));
    __shared__ float wmax[4];
    if ((threadIdx.x & 63) == 0) wmax[threadIdx.x >> 6] = m;
    __syncthreads();
    if (threadIdx.x == 0)
        partials[blockIdx.x] = fmaxf(fmaxf(wmax[0], wmax[1]),
                                     fmaxf(wmax[2], wmax[3]));
}

// ---------------- fused: reduce partials, quantize W, cast x ---------------
__global__ void quantcast_kernel(const float* __restrict__ W,
                                 const float* __restrict__ X,
                                 const float* __restrict__ partials,
                                 unsigned short* __restrict__ Wq,
                                 unsigned short* __restrict__ Xb,
                                 int nw4, int nx4) {
    float m = fmaxf(partials[threadIdx.x], partials[threadIdx.x + 256]);
    #pragma unroll
    for (int off = 32; off > 0; off >>= 1)
        m = fmaxf(m, __shfl_down(m, off));
    __shared__ float smax[4];
    if ((threadIdx.x & 63) == 0) smax[threadIdx.x >> 6] = m;
    __syncthreads();
    const float amax = fmaxf(fmaxf(smax[0], smax[1]), fmaxf(smax[2], smax[3]));
    const float scale = amax / 127.0f;
    const float inv_scale = 127.0f / amax;

    int i0 = blockIdx.x * blockDim.x + threadIdx.x;
    int stride = gridDim.x * blockDim.x;
    for (int idx = i0; idx < nw4; idx += stride) {
        float4 w = ((const float4*)W)[idx];
        float q0 = fminf(fmaxf(rintf(w.x * inv_scale), -127.f), 127.f) * scale;
        float q1 = fminf(fmaxf(rintf(w.y * inv_scale), -127.f), 127.f) * scale;
        float q2 = fminf(fmaxf(rintf(w.z * inv_scale), -127.f), 127.f) * scale;
        float q3 = fminf(fmaxf(rintf(w.w * inv_scale), -127.f), 127.f) * scale;
        ushort4 o;
        o.x = f2bf(q0); o.y = f2bf(q1); o.z = f2bf(q2); o.w = f2bf(q3);
        ((ushort4*)Wq)[idx] = o;
    }
    for (int idx = i0; idx < nx4; idx += stride) {
        float4 v = ((const float4*)X)[idx];
        ushort4 o;
        o.x = f2bf(v.x); o.y = f2bf(v.y); o.z = f2bf(v.z); o.w = f2bf(v.w);
        ((ushort4*)Xb)[idx] = o;
    }
}

// ---------------- bf16 NT GEMM: C[M,N] = A[M,K] * B[N,K]^T + bias ----------
// 256x256 tile, BK=64, 512 threads = 8 waves as 2(M)x4(N); per-wave output
// 128x64 as 8x4 fragments of mfma_f32_16x16x32_bf16 (2 k-steps per K-tile).
//
// LDS: lds[buf][mat][half][128*64] bf16 = 128 KiB. A-half h = tile rows
// h*128..+128; B-half h = tile cols h*128..+128. Within a half, (row, 16B
// chunk cc) is stored at chunk position cc ^ (row&7) (conflict-free for the
// fragment read pattern: 8 lanes per 16B slot). global_load_lds writes LDS
// linearly (thread t -> byte t*16), so the *global* source column is
// pre-swizzled: thread t loads chunk (t&7) ^ ((t>>3)&7) of its row.
//
// Phase schedule per K-tile kt (buf p = kt&1), quadrants in DESCENDING row
// order (q3=rows96-127 first) so staged regions are provably dead:
//   p1: read B(8) + A q3(4); stage S1 = (kt+1).A rows0-63 -> buf p^1
//   p2: read A q2;           stage S2 = (kt+2).B half0    -> buf p
//   p3: read A q1;           stage S3 = (kt+2).B half1    -> buf p
//   p4: read A q0;           stage S4 = (kt+2).A rows64-127 -> buf p
//       then s_waitcnt vmcnt(6): guarantees all of tile kt+1 landed while
//       leaving tile kt+2's 6 loads in flight (never drains to 0 mid-loop).
// Each phase: [ds_read | stage] ; s_barrier ; lgkmcnt(0)+sched_barrier ;
//             setprio(1) ; 16 MFMA ; setprio(0) ; s_barrier.
typedef __attribute__((address_space(3))) void lds_void;
typedef __attribute__((address_space(1))) void gbl_void;

__global__ __launch_bounds__(512, 2) void gemm_bt(
    const unsigned short* __restrict__ A,   // [M,K] bf16 bits
    const unsigned short* __restrict__ B,   // [N,K] bf16 bits
    const float* __restrict__ bias,         // [N]
    float* __restrict__ C, int M, int N, int K)
{
    __shared__ __align__(16) unsigned short lds[2][2][2][128 * 64]; // 128 KiB

    const int tid  = threadIdx.x;
    const int wave = tid >> 6;
    const int lane = tid & 63;
    const int wr   = wave >> 2;            // 0..1 : M-half
    const int wc   = wave & 3;             // 0..3 : N-quarter
    const int r    = lane & 15;
    const int g    = lane >> 4;

    // XCD-aware block swizzle (nwg = 512, divisible by 8 -> bijective)
    const int nwg  = gridDim.x;
    const int orig = blockIdx.x;
    const int swz  = ((nwg & 7) == 0) ? ((orig & 7) * (nwg >> 3) + (orig >> 3))
                                      : orig;
    const int tN = N / BN;
    const int bn = swz % tN;
    const int bm = swz / tN;
    const int rowBase = bm * BM;
    const int colBase = bn * BN;

    // ---- staging geometry: thread t -> LDS byte t*16 of a 64-row slab ----
    const int srow = tid >> 3;                         // 0..63 within slab
    const int scol = (((tid & 7) ^ (srow & 7)) << 3);  // pre-swizzled elem col
    const unsigned short* aS = A + (size_t)(rowBase + srow) * K + scol;
    const unsigned short* bS = B + (size_t)(colBase + srow) * K + scol;
    const int dstOff = wave * 512;   // elements; lane*16B added by hardware

#define STG_A(P_, H_, S_, K0_) __builtin_amdgcn_global_load_lds(              \
    (gbl_void*)(aS + (size_t)((H_) * 128 + (S_) * 64) * K + (K0_)),           \
    (lds_void*)&lds[P_][0][H_][(S_) * 4096 + dstOff], 16, 0, 0)
#define STG_B(P_, H_, S_, K0_) __builtin_amdgcn_global_load_lds(              \
    (gbl_void*)(bS + (size_t)((H_) * 128 + (S_) * 64) * K + (K0_)),           \
    (lds_void*)&lds[P_][1][H_][(S_) * 4096 + dstOff], 16, 0, 0)

    // ---- fragment read geometry (mfma_f32_16x16x32: lane r+16g holds
    //      row r, k = 8g..8g+8 of the 32-wide k-step) ----
    const int sw    = r & 7;
    const int coff0 = ((g    ) ^ sw) << 3;   // k-step 0 chunk, swizzled
    const int coff1 = ((g + 4) ^ sw) << 3;   // k-step 1 chunk, swizzled
    const int aRowOff = r * 64;
    const int bRowOff = ((wc & 1) * 64 + r) * 64;

    f32x4 acc[8][4];
    #pragma unroll
    for (int i = 0; i < 8; ++i)
        #pragma unroll
        for (int j = 0; j < 4; ++j)
            #pragma unroll
            for (int e = 0; e < 4; ++e)
                acc[i][j][e] = 0.f;

    const int KT = K >> 6;   // K-tiles of 64

    // ---- prologue: tile0 fully (8 loads), tile1 all but A-low (6 loads) ----
    STG_B(0, 0, 0, 0); STG_B(0, 0, 1, 0); STG_B(0, 1, 0, 0); STG_B(0, 1, 1, 0);
    STG_A(0, 0, 0, 0); STG_A(0, 0, 1, 0); STG_A(0, 1, 0, 0); STG_A(0, 1, 1, 0);
    if (KT > 1) {
        STG_B(1, 0, 0, BK); STG_B(1, 0, 1, BK);
        STG_B(1, 1, 0, BK); STG_B(1, 1, 1, BK);
        STG_A(1, 0, 1, BK); STG_A(1, 1, 1, BK);
        asm volatile("s_waitcnt vmcnt(6)" ::: "memory");
    } else {
        asm volatile("s_waitcnt vmcnt(0)" ::: "memory");
    }
    __builtin_amdgcn_s_barrier();

#define PHASE_COMPUTE(MF0)                                                    \
  {                                                                           \
    short8 af0k0 = *(const short8*)(sA + (MF0) * 1024 + aRowOff + coff0);     \
    short8 af0k1 = *(const short8*)(sA + (MF0) * 1024 + aRowOff + coff1);     \
    short8 af1k0 = *(const short8*)(sA + ((MF0) + 1) * 1024 + aRowOff + coff0); \
    short8 af1k1 = *(const short8*)(sA + ((MF0) + 1) * 1024 + aRowOff + coff1); \
    __builtin_amdgcn_s_barrier();                                             \
    asm volatile("s_waitcnt lgkmcnt(0)" ::: "memory");                        \
    __builtin_amdgcn_sched_barrier(0);                                        \
    __builtin_amdgcn_s_setprio(1);                                            \
    _Pragma("unroll")                                                         \
    for (int nf = 0; nf < 4; ++nf) {                                          \
        acc[(MF0)][nf]     = __builtin_amdgcn_mfma_f32_16x16x32_bf16(         \
            af0k0, bfr[nf][0], acc[(MF0)][nf], 0, 0, 0);                      \
        acc[(MF0) + 1][nf] = __builtin_amdgcn_mfma_f32_16x16x32_bf16(         \
            af1k0, bfr[nf][0], acc[(MF0) + 1][nf], 0, 0, 0);                  \
        acc[(MF0)][nf]     = __builtin_amdgcn_mfma_f32_16x16x32_bf16(         \
            af0k1, bfr[nf][1], acc[(MF0)][nf], 0, 0, 0);                      \
        acc[(MF0) + 1][nf] = __builtin_amdgcn_mfma_f32_16x16x32_bf16(         \
            af1k1, bfr[nf][1], acc[(MF0) + 1][nf], 0, 0, 0);                  \
    }                                                                         \
    __builtin_amdgcn_s_setprio(0);                                            \
    __builtin_amdgcn_s_barrier();                                             \
  }

    for (int kt = 0; kt < KT; ++kt) {
        const int p  = kt & 1;
        const int pn = p ^ 1;
        const unsigned short* sA = &lds[p][0][wr][0];
        const unsigned short* sB = &lds[p][1][wc >> 1][0];
        const bool s1 = (kt + 1) < KT;
        const bool s2 = (kt + 2) < KT;
        const int kA = (kt + 1) << 6;
        const int kB = (kt + 2) << 6;

        // ---- phase 1: B frags (whole K-tile) + A quad3 (rows 96-127) ----
        short8 bfr[4][2];
        #pragma unroll
        for (int nf = 0; nf < 4; ++nf) {
            bfr[nf][0] = *(const short8*)(sB + nf * 1024 + bRowOff + coff0);
            bfr[nf][1] = *(const short8*)(sB + nf * 1024 + bRowOff + coff1);
        }
        if (s1) { STG_A(pn, 0, 0, kA); STG_A(pn, 1, 0, kA); }   // S1
        PHASE_COMPUTE(6)

        // ---- phase 2: A quad2 (rows 64-95) ----
        if (s2) { STG_B(p, 0, 0, kB); STG_B(p, 0, 1, kB); }     // S2
        PHASE_COMPUTE(4)

        // ---- phase 3: A quad1 (rows 32-63) ----
        if (s2) { STG_B(p, 1, 0, kB); STG_B(p, 1, 1, kB); }     // S3
        PHASE_COMPUTE(2)

        // ---- phase 4: A quad0 (rows 0-31) + counted tile-boundary wait ----
        if (s2) { STG_A(p, 0, 1, kB); STG_A(p, 1, 1, kB); }     // S4
        if (s2) asm volatile("s_waitcnt vmcnt(6)" ::: "memory");
        else    asm volatile("s_waitcnt vmcnt(0)" ::: "memory");
        PHASE_COMPUTE(0)
    }

    // ---- epilogue: C/D layout col = lane&15, row = (lane>>4)*4 + reg ----
    const int ecol  = colBase + wc * 64 + r;
    const int erow0 = rowBase + wr * 128 + g * 4;
    #pragma unroll
    for (int nf = 0; nf < 4; ++nf) {
        const int col = ecol + nf * 16;
        const float bv = bias[col];
        #pragma unroll
        for (int mf = 0; mf < 8; ++mf) {
            const int row0 = erow0 + mf * 16;
            #pragma unroll
            for (int j = 0; j < 4; ++j)
                C[(size_t)(row0 + j) * N + col] = acc[mf][nf][j] + bv;
        }
    }
#undef PHASE_COMPUTE
#undef STG_A
#undef STG_B
}

// ---------------------------------------------------------------------------
extern "C" void kernel_launch(void* const* d_in, const int* in_sizes, int n_in,
                              void* d_out, int out_size, void* d_ws, size_t ws_size,
                              hipStream_t stream) {
    const float* x = (const float*)d_in[0];   // [M,K]
    const float* W = (const float*)d_in[1];   // [N,K]
    const float* b = (const float*)d_in[2];   // [N]
    float* out = (float*)d_out;               // [M,N]

    const int N = in_sizes[2];                // 4096
    const int K = in_sizes[1] / N;            // 4096
    const int M = in_sizes[0] / K;            // 8192

    unsigned char* ws = (unsigned char*)d_ws;
    float* partials = (float*)ws;             // PMAX_BLOCKS floats
    unsigned short* xb = (unsigned short*)(ws + 4096);
    unsigned short* wq = (unsigned short*)(ws + 4096 + (size_t)M * K * 2);

    partial_max_kernel<<<PMAX_BLOCKS, 256, 0, stream>>>(W, partials, (N * K) / 4);
    quantcast_kernel<<<8192, 256, 0, stream>>>(W, x, partials, wq, xb,
                                               (N * K) / 4, (M * K) / 4);

    dim3 grid((N / BN) * (M / BM));           // 16*32 = 512, 1D for swizzle
    gemm_bt<<<grid, 512, 0, stream>>>(xb, wq, b, out, M, N, K);
}

// Round 2
// 508.015 us; speedup vs baseline: 1.2764x; 1.0045x over previous
//
#include <hip/hip_runtime.h>
#include <hip/hip_bf16.h>
#include <stdint.h>

// ---------------------------------------------------------------------------
// Int8Linear: y = x @ Wq^T + b, Wq = dequant(int8-quant(W)) per-tensor absmax.
// R6: (a) GEMM keeps the R5 256x256/BK=64/8-wave 4-phase pipeline but moves
//     all ds_reads into the PREVIOUS phase's MFMA shadow (issued after the
//     MFMA cluster, before the end barrier). Tile-boundary reads are legal in
//     phase 4's shadow because after B1(ph4) every wave has passed vmcnt(6),
//     so tile kt+1 is globally landed. Phase-1's 12-read spike drops to 4.
//     Shadow loads reuse the just-consumed fragment registers (no VGPR cost).
//     MFMA order k0-octet then k1-octet (acc dep distance 8).
// (b) Pre-pass: K1 fuses X->bf16 cast with W partial-absmax (1024 blocks);
//     K2 quantizes W only (2048 blocks). Same bytes, better balance — also a
//     diagnostic for whether the ~245us non-gemm time is kernel or harness.
// Workspace: [0..4KB) partial maxima | 4096 + x_bf16 (64MiB) | wq_bf16 (32MiB)
// ---------------------------------------------------------------------------

typedef __attribute__((ext_vector_type(8))) short short8;    // 8 x bf16
typedef __attribute__((ext_vector_type(4))) float f32x4;     // 16x16 acc

#define BM 256
#define BN 256
#define BK 64
#define PREP_BLOCKS 1024

// float -> bf16, round-to-nearest-even
__device__ __forceinline__ unsigned short f2bf(float f) {
    unsigned u = __float_as_uint(f);
    unsigned r = 0x7fffu + ((u >> 16) & 1u);
    return (unsigned short)((u + r) >> 16);
}

// ---------------- K1: fused X-cast + per-block partial absmax of W ---------
__global__ void prep_kernel(const float* __restrict__ W,
                            const float* __restrict__ X,
                            unsigned short* __restrict__ Xb,
                            float* __restrict__ partials,
                            int nw4, int nx4) {
    int i0 = blockIdx.x * blockDim.x + threadIdx.x;
    int stride = gridDim.x * blockDim.x;
    float m = 0.f;
    for (int idx = i0; idx < nw4; idx += stride) {
        float4 v = ((const float4*)W)[idx];
        m = fmaxf(m, fmaxf(fmaxf(fabsf(v.x), fabsf(v.y)),
                           fmaxf(fabsf(v.z), fabsf(v.w))));
    }
    for (int idx = i0; idx < nx4; idx += stride) {
        float4 v = ((const float4*)X)[idx];
        ushort4 o;
        o.x = f2bf(v.x); o.y = f2bf(v.y); o.z = f2bf(v.z); o.w = f2bf(v.w);
        ((ushort4*)Xb)[idx] = o;
    }
    #pragma unroll
    for (int off = 32; off > 0; off >>= 1)
        m = fmaxf(m, __shfl_down(m, off));
    __shared__ float wmax[4];
    if ((threadIdx.x & 63) == 0) wmax[threadIdx.x >> 6] = m;
    __syncthreads();
    if (threadIdx.x == 0)
        partials[blockIdx.x] = fmaxf(fmaxf(wmax[0], wmax[1]),
                                     fmaxf(wmax[2], wmax[3]));
}

// ---------------- K2: reduce partials, quantize W to bf16 ------------------
__global__ void quantw_kernel(const float* __restrict__ W,
                              const float* __restrict__ partials,
                              unsigned short* __restrict__ Wq, int nw4) {
    // every block redundantly reduces the 1024 partials (4 KB, L2-hot)
    float m = fmaxf(fmaxf(partials[threadIdx.x], partials[threadIdx.x + 256]),
                    fmaxf(partials[threadIdx.x + 512], partials[threadIdx.x + 768]));
    #pragma unroll
    for (int off = 32; off > 0; off >>= 1)
        m = fmaxf(m, __shfl_down(m, off));
    __shared__ float smax[4];
    if ((threadIdx.x & 63) == 0) smax[threadIdx.x >> 6] = m;
    __syncthreads();
    const float amax = fmaxf(fmaxf(smax[0], smax[1]), fmaxf(smax[2], smax[3]));
    const float scale = amax / 127.0f;
    const float inv_scale = 127.0f / amax;

    int i0 = blockIdx.x * blockDim.x + threadIdx.x;
    int stride = gridDim.x * blockDim.x;
    for (int idx = i0; idx < nw4; idx += stride) {
        float4 w = ((const float4*)W)[idx];
        float q0 = fminf(fmaxf(rintf(w.x * inv_scale), -127.f), 127.f) * scale;
        float q1 = fminf(fmaxf(rintf(w.y * inv_scale), -127.f), 127.f) * scale;
        float q2 = fminf(fmaxf(rintf(w.z * inv_scale), -127.f), 127.f) * scale;
        float q3 = fminf(fmaxf(rintf(w.w * inv_scale), -127.f), 127.f) * scale;
        ushort4 o;
        o.x = f2bf(q0); o.y = f2bf(q1); o.z = f2bf(q2); o.w = f2bf(q3);
        ((ushort4*)Wq)[idx] = o;
    }
}

// ---------------- bf16 NT GEMM: C[M,N] = A[M,K] * B[N,K]^T + bias ----------
// Geometry identical to R5 (see R5 header). R6 change: read scheduling.
// Steady-state tile kt (buf p), per phase:
//   ph1(q3): pre: S1 stage + B-k1 reads(4); B1; lgkm; MFMA q3; shadow: A-q2(4)
//   ph2(q2): pre: S2;                       B1; lgkm; MFMA q2; shadow: A-q1(4)
//   ph3(q1): pre: S3;                       B1; lgkm; MFMA q1; shadow: A-q0(4)
//   ph4(q0): pre: S4 + vmcnt(6);            B1; lgkm; MFMA q0;
//            shadow: next-tile B-k0(4) + A-q3(4)   [legal: post-B1(ph4) all
//            waves passed vmcnt(6) => tile kt+1 globally landed]
// Overwrite ledger (stage vs reads of the region):
//   S1(kt+1) writes buf p A slab0: q1/q0 shadow reads complete <= B2(ph4,kt),
//     S1 issues after B2(ph4,kt).  S4(kt) writes buf p A slab1: q2 shadow read
//     completes <= B2(ph2), q3 read completed previous tile; S4 issues after
//     B2(ph3).  S2/S3(kt) write buf p B: B reads complete <= B1(ph1)+lgkm,
//     S2 issues after B2(ph1).  All safe with >=1 barrier of margin.
typedef __attribute__((address_space(3))) void lds_void;
typedef __attribute__((address_space(1))) void gbl_void;

__global__ __launch_bounds__(512, 2) void gemm_bt(
    const unsigned short* __restrict__ A,   // [M,K] bf16 bits
    const unsigned short* __restrict__ B,   // [N,K] bf16 bits
    const float* __restrict__ bias,         // [N]
    float* __restrict__ C, int M, int N, int K)
{
    __shared__ __align__(16) unsigned short lds[2][2][2][128 * 64]; // 128 KiB

    const int tid  = threadIdx.x;
    const int wave = tid >> 6;
    const int lane = tid & 63;
    const int wr   = wave >> 2;            // 0..1 : M-half
    const int wc   = wave & 3;             // 0..3 : N-quarter
    const int r    = lane & 15;
    const int g    = lane >> 4;

    // XCD-aware block swizzle (nwg = 512, divisible by 8 -> bijective)
    const int nwg  = gridDim.x;
    const int orig = blockIdx.x;
    const int swz  = ((nwg & 7) == 0) ? ((orig & 7) * (nwg >> 3) + (orig >> 3))
                                      : orig;
    const int tN = N / BN;
    const int bn = swz % tN;
    const int bm = swz / tN;
    const int rowBase = bm * BM;
    const int colBase = bn * BN;

    // ---- staging geometry: thread t -> LDS byte t*16 of a 64-row slab ----
    const int srow = tid >> 3;                         // 0..63 within slab
    const int scol = (((tid & 7) ^ (srow & 7)) << 3);  // pre-swizzled elem col
    const unsigned short* aS = A + (size_t)(rowBase + srow) * K + scol;
    const unsigned short* bS = B + (size_t)(colBase + srow) * K + scol;
    const int dstOff = wave * 512;   // elements; lane*16B added by hardware

#define STG_A(P_, H_, S_, K0_) __builtin_amdgcn_global_load_lds(              \
    (gbl_void*)(aS + (size_t)((H_) * 128 + (S_) * 64) * K + (K0_)),           \
    (lds_void*)&lds[P_][0][H_][(S_) * 4096 + dstOff], 16, 0, 0)
#define STG_B(P_, H_, S_, K0_) __builtin_amdgcn_global_load_lds(              \
    (gbl_void*)(bS + (size_t)((H_) * 128 + (S_) * 64) * K + (K0_)),           \
    (lds_void*)&lds[P_][1][H_][(S_) * 4096 + dstOff], 16, 0, 0)

    // ---- fragment read geometry (mfma_f32_16x16x32: lane r+16g holds
    //      row r, k = 8g..8g+8 of the 32-wide k-step) ----
    const int sw    = r & 7;
    const int coff0 = ((g    ) ^ sw) << 3;   // k-step 0 chunk, swizzled
    const int coff1 = ((g + 4) ^ sw) << 3;   // k-step 1 chunk, swizzled
    const int aRowOff = r * 64;
    const int bRowOff = ((wc & 1) * 64 + r) * 64;

#define LDA(S_, MF_, C_) (*(const short8*)((S_) + (MF_) * 1024 + aRowOff + (C_)))
#define LDB(S_, NF_, C_) (*(const short8*)((S_) + (NF_) * 1024 + bRowOff + (C_)))
#define MM(ACC_, AV_, BV_) ACC_ = __builtin_amdgcn_mfma_f32_16x16x32_bf16(    \
    AV_, BV_, ACC_, 0, 0, 0)

    f32x4 acc[8][4];
    #pragma unroll
    for (int i = 0; i < 8; ++i)
        #pragma unroll
        for (int j = 0; j < 4; ++j)
            #pragma unroll
            for (int e = 0; e < 4; ++e)
                acc[i][j][e] = 0.f;

    const int KT = K >> 6;   // K-tiles of 64

    // ---- prologue: tile0 fully (8 loads), tile1 all but A-slab0 (6) ----
    STG_B(0, 0, 0, 0); STG_B(0, 0, 1, 0); STG_B(0, 1, 0, 0); STG_B(0, 1, 1, 0);
    STG_A(0, 0, 0, 0); STG_A(0, 0, 1, 0); STG_A(0, 1, 0, 0); STG_A(0, 1, 1, 0);
    if (KT > 1) {
        STG_B(1, 0, 0, BK); STG_B(1, 0, 1, BK);
        STG_B(1, 1, 0, BK); STG_B(1, 1, 1, BK);
        STG_A(1, 0, 1, BK); STG_A(1, 1, 1, BK);
        asm volatile("s_waitcnt vmcnt(6)" ::: "memory");
    } else {
        asm volatile("s_waitcnt vmcnt(0)" ::: "memory");
    }
    __builtin_amdgcn_s_barrier();

    // ---- pre-loop reads: tile0 B-k0 + A-q3 (steady-state entry state) ----
    short8 b00, b10, b20, b30;            // B k-step 0, nf 0..3
    short8 b01, b11, b21, b31;            // B k-step 1
    short8 a0, a1, a2, a3;                // current A quad: (mf0,k0),(mf0,k1),(mf1,k0),(mf1,k1)
    {
        const unsigned short* sA0 = &lds[0][0][wr][0];
        const unsigned short* sB0 = &lds[0][1][wc >> 1][0];
        b00 = LDB(sB0, 0, coff0); b10 = LDB(sB0, 1, coff0);
        b20 = LDB(sB0, 2, coff0); b30 = LDB(sB0, 3, coff0);
        a0 = LDA(sA0, 6, coff0);  a1 = LDA(sA0, 6, coff1);
        a2 = LDA(sA0, 7, coff0);  a3 = LDA(sA0, 7, coff1);
    }

// B1; lgkm; [fence]; prio1; 16 MFMA (k0 octet then k1 octet); prio0; [fence]
#define COMPUTE(MF0)                                                          \
    __builtin_amdgcn_s_barrier();                                             \
    asm volatile("s_waitcnt lgkmcnt(0)" ::: "memory");                        \
    __builtin_amdgcn_sched_barrier(0);                                        \
    __builtin_amdgcn_s_setprio(1);                                            \
    MM(acc[MF0][0], a0, b00); MM(acc[(MF0)+1][0], a2, b00);                   \
    MM(acc[MF0][1], a0, b10); MM(acc[(MF0)+1][1], a2, b10);                   \
    MM(acc[MF0][2], a0, b20); MM(acc[(MF0)+1][2], a2, b20);                   \
    MM(acc[MF0][3], a0, b30); MM(acc[(MF0)+1][3], a2, b30);                   \
    MM(acc[MF0][0], a1, b01); MM(acc[(MF0)+1][0], a3, b01);                   \
    MM(acc[MF0][1], a1, b11); MM(acc[(MF0)+1][1], a3, b11);                   \
    MM(acc[MF0][2], a1, b21); MM(acc[(MF0)+1][2], a3, b21);                   \
    MM(acc[MF0][3], a1, b31); MM(acc[(MF0)+1][3], a3, b31);                   \
    __builtin_amdgcn_s_setprio(0);                                            \
    __builtin_amdgcn_sched_barrier(0);

    for (int kt = 0; kt < KT; ++kt) {
        const int p  = kt & 1;
        const int pn = p ^ 1;
        const unsigned short* sA  = &lds[p][0][wr][0];
        const unsigned short* sB  = &lds[p][1][wc >> 1][0];
        const unsigned short* sAn = &lds[pn][0][wr][0];
        const unsigned short* sBn = &lds[pn][1][wc >> 1][0];
        const bool s1 = (kt + 1) < KT;
        const bool s2 = (kt + 2) < KT;
        const int kA = (kt + 1) << 6;
        const int kB = (kt + 2) << 6;

        // ---- phase 1 (q3): pre: S1 + B-k1 reads ----
        if (s1) { STG_A(pn, 0, 0, kA); STG_A(pn, 1, 0, kA); }
        b01 = LDB(sB, 0, coff1); b11 = LDB(sB, 1, coff1);
        b21 = LDB(sB, 2, coff1); b31 = LDB(sB, 3, coff1);
        COMPUTE(6)
        a0 = LDA(sA, 4, coff0); a1 = LDA(sA, 4, coff1);     // shadow: A-q2
        a2 = LDA(sA, 5, coff0); a3 = LDA(sA, 5, coff1);
        __builtin_amdgcn_s_barrier();

        // ---- phase 2 (q2) ----
        if (s2) { STG_B(p, 0, 0, kB); STG_B(p, 0, 1, kB); }
        COMPUTE(4)
        a0 = LDA(sA, 2, coff0); a1 = LDA(sA, 2, coff1);     // shadow: A-q1
        a2 = LDA(sA, 3, coff0); a3 = LDA(sA, 3, coff1);
        __builtin_amdgcn_s_barrier();

        // ---- phase 3 (q1) ----
        if (s2) { STG_B(p, 1, 0, kB); STG_B(p, 1, 1, kB); }
        COMPUTE(2)
        a0 = LDA(sA, 0, coff0); a1 = LDA(sA, 0, coff1);     // shadow: A-q0
        a2 = LDA(sA, 1, coff0); a3 = LDA(sA, 1, coff1);
        __builtin_amdgcn_s_barrier();

        // ---- phase 4 (q0): counted tile-boundary wait ----
        if (s2) { STG_A(p, 0, 1, kB); STG_A(p, 1, 1, kB); }
        if (s2) asm volatile("s_waitcnt vmcnt(6)" ::: "memory");
        else    asm volatile("s_waitcnt vmcnt(0)" ::: "memory");
        COMPUTE(0)
        if (s1) {                                           // shadow: next tile
            b00 = LDB(sBn, 0, coff0); b10 = LDB(sBn, 1, coff0);
            b20 = LDB(sBn, 2, coff0); b30 = LDB(sBn, 3, coff0);
            a0 = LDA(sAn, 6, coff0);  a1 = LDA(sAn, 6, coff1);
            a2 = LDA(sAn, 7, coff0);  a3 = LDA(sAn, 7, coff1);
        }
        __builtin_amdgcn_s_barrier();
    }

    // ---- epilogue: C/D layout col = lane&15, row = (lane>>4)*4 + reg ----
    const int ecol  = colBase + wc * 64 + r;
    const int erow0 = rowBase + wr * 128 + g * 4;
    #pragma unroll
    for (int nf = 0; nf < 4; ++nf) {
        const int col = ecol + nf * 16;
        const float bv = bias[col];
        #pragma unroll
        for (int mf = 0; mf < 8; ++mf) {
            const int row0 = erow0 + mf * 16;
            #pragma unroll
            for (int j = 0; j < 4; ++j)
                C[(size_t)(row0 + j) * N + col] = acc[mf][nf][j] + bv;
        }
    }
#undef COMPUTE
#undef MM
#undef LDA
#undef LDB
#undef STG_A
#undef STG_B
}

// ---------------------------------------------------------------------------
extern "C" void kernel_launch(void* const* d_in, const int* in_sizes, int n_in,
                              void* d_out, int out_size, void* d_ws, size_t ws_size,
                              hipStream_t stream) {
    const float* x = (const float*)d_in[0];   // [M,K]
    const float* W = (const float*)d_in[1];   // [N,K]
    const float* b = (const float*)d_in[2];   // [N]
    float* out = (float*)d_out;               // [M,N]

    const int N = in_sizes[2];                // 4096
    const int K = in_sizes[1] / N;            // 4096
    const int M = in_sizes[0] / K;            // 8192

    unsigned char* ws = (unsigned char*)d_ws;
    float* partials = (float*)ws;             // PREP_BLOCKS floats (4 KB)
    unsigned short* xb = (unsigned short*)(ws + 4096);
    unsigned short* wq = (unsigned short*)(ws + 4096 + (size_t)M * K * 2);

    prep_kernel<<<PREP_BLOCKS, 256, 0, stream>>>(W, x, xb, partials,
                                                 (N * K) / 4, (M * K) / 4);
    quantw_kernel<<<2048, 256, 0, stream>>>(W, partials, wq, (N * K) / 4);

    dim3 grid((N / BN) * (M / BM));           // 16*32 = 512, 1D for swizzle
    gemm_bt<<<grid, 512, 0, stream>>>(xb, wq, b, out, M, N, K);
}

// Round 4
// 502.659 us; speedup vs baseline: 1.2900x; 1.0107x over previous
//
#include <hip/hip_runtime.h>
#include <hip/hip_bf16.h>
#include <stdint.h>

// ---------------------------------------------------------------------------
// Int8Linear: y = x @ Wq^T + b, Wq = dequant(int8-quant(W)) per-tensor absmax.
// R7 (resubmit; R3's bench was a container-infra failure, no data): GEMM
//     keeps R6's 256x256/BK=64/8-wave 4-phase pipeline + staging ledger, but
//     interleaves the ds_reads INTO the MFMA instruction stream via
//     sched_group_barrier (MFMA=0x8, DS_READ=0x100). Mechanism: MFMA issue is
//     throughput-blocking, so reads placed after the cluster only issue once
//     the matrix pipe drains; interleaved reads issue into the idle LDS pipe
//     during MFMA issue stalls, hiding the ~2300 cyc/tile of ds_read under
//     the 2484 cyc/tile MFMA window. Reads are one phase ahead (ph1->q2,
//     ph2->q1, ph3->q0, ph4->next-tile B-k0 + A-q3). Last tile peeled so
//     clusters are branch-free. Barriers/staging/vmcnt ledger identical to R6.
// Pre-pass unchanged (isolate the GEMM variable).
// Workspace: [0..4KB) partial maxima | 4096 + x_bf16 (64MiB) | wq_bf16 (32MiB)
// ---------------------------------------------------------------------------

typedef __attribute__((ext_vector_type(8))) short short8;    // 8 x bf16
typedef __attribute__((ext_vector_type(4))) float f32x4;     // 16x16 acc

#define BM 256
#define BN 256
#define BK 64
#define PREP_BLOCKS 1024

// float -> bf16, round-to-nearest-even
__device__ __forceinline__ unsigned short f2bf(float f) {
    unsigned u = __float_as_uint(f);
    unsigned r = 0x7fffu + ((u >> 16) & 1u);
    return (unsigned short)((u + r) >> 16);
}

// ---------------- K1: fused X-cast + per-block partial absmax of W ---------
__global__ void prep_kernel(const float* __restrict__ W,
                            const float* __restrict__ X,
                            unsigned short* __restrict__ Xb,
                            float* __restrict__ partials,
                            int nw4, int nx4) {
    int i0 = blockIdx.x * blockDim.x + threadIdx.x;
    int stride = gridDim.x * blockDim.x;
    float m = 0.f;
    for (int idx = i0; idx < nw4; idx += stride) {
        float4 v = ((const float4*)W)[idx];
        m = fmaxf(m, fmaxf(fmaxf(fabsf(v.x), fabsf(v.y)),
                           fmaxf(fabsf(v.z), fabsf(v.w))));
    }
    for (int idx = i0; idx < nx4; idx += stride) {
        float4 v = ((const float4*)X)[idx];
        ushort4 o;
        o.x = f2bf(v.x); o.y = f2bf(v.y); o.z = f2bf(v.z); o.w = f2bf(v.w);
        ((ushort4*)Xb)[idx] = o;
    }
    #pragma unroll
    for (int off = 32; off > 0; off >>= 1)
        m = fmaxf(m, __shfl_down(m, off));
    __shared__ float wmax[4];
    if ((threadIdx.x & 63) == 0) wmax[threadIdx.x >> 6] = m;
    __syncthreads();
    if (threadIdx.x == 0)
        partials[blockIdx.x] = fmaxf(fmaxf(wmax[0], wmax[1]),
                                     fmaxf(wmax[2], wmax[3]));
}

// ---------------- K2: reduce partials, quantize W to bf16 ------------------
__global__ void quantw_kernel(const float* __restrict__ W,
                              const float* __restrict__ partials,
                              unsigned short* __restrict__ Wq, int nw4) {
    float m = fmaxf(fmaxf(partials[threadIdx.x], partials[threadIdx.x + 256]),
                    fmaxf(partials[threadIdx.x + 512], partials[threadIdx.x + 768]));
    #pragma unroll
    for (int off = 32; off > 0; off >>= 1)
        m = fmaxf(m, __shfl_down(m, off));
    __shared__ float smax[4];
    if ((threadIdx.x & 63) == 0) smax[threadIdx.x >> 6] = m;
    __syncthreads();
    const float amax = fmaxf(fmaxf(smax[0], smax[1]), fmaxf(smax[2], smax[3]));
    const float scale = amax / 127.0f;
    const float inv_scale = 127.0f / amax;

    int i0 = blockIdx.x * blockDim.x + threadIdx.x;
    int stride = gridDim.x * blockDim.x;
    for (int idx = i0; idx < nw4; idx += stride) {
        float4 w = ((const float4*)W)[idx];
        float q0 = fminf(fmaxf(rintf(w.x * inv_scale), -127.f), 127.f) * scale;
        float q1 = fminf(fmaxf(rintf(w.y * inv_scale), -127.f), 127.f) * scale;
        float q2 = fminf(fmaxf(rintf(w.z * inv_scale), -127.f), 127.f) * scale;
        float q3 = fminf(fmaxf(rintf(w.w * inv_scale), -127.f), 127.f) * scale;
        ushort4 o;
        o.x = f2bf(q0); o.y = f2bf(q1); o.z = f2bf(q2); o.w = f2bf(q3);
        ((ushort4*)Wq)[idx] = o;
    }
}

// ---------------- bf16 NT GEMM: C[M,N] = A[M,K] * B[N,K]^T + bias ----------
// Geometry identical to R5/R6 (see R5 header). R7 change: in-cluster reads.
// Steady-state tile kt (buf p):
//   ph1(q3): pre: S1 + B-k1 reads(4); cluster: 16 MFMA ⊕ 4 reads (A-q2)
//   ph2(q2): pre: S2;                 cluster: 16 MFMA ⊕ 4 reads (A-q1)
//   ph3(q1): pre: S3;                 cluster: 16 MFMA ⊕ 4 reads (A-q0)
//   ph4(q0): pre: S4 + vmcnt(6);      cluster: 16 MFMA ⊕ 8 reads
//            (next-tile B-k0 -> nb, A-q3 -> x; legal: post-B1(ph4) all waves
//             passed vmcnt(6) => tile kt+1 globally landed)
// Cluster = B1; lgkmcnt(0); sched_barrier; setprio(1); [MFMA⊕DS via
// sched_group_barrier]; sched_barrier; setprio(0); B2.  Overwrite ledger
// identical to R6 (reads occupy the same barrier interval as R6's shadows).
typedef __attribute__((address_space(3))) void lds_void;
typedef __attribute__((address_space(1))) void gbl_void;

__global__ __launch_bounds__(512, 2) void gemm_bt(
    const unsigned short* __restrict__ A,   // [M,K] bf16 bits
    const unsigned short* __restrict__ B,   // [N,K] bf16 bits
    const float* __restrict__ bias,         // [N]
    float* __restrict__ C, int M, int N, int K)
{
    __shared__ __align__(16) unsigned short lds[2][2][2][128 * 64]; // 128 KiB

    const int tid  = threadIdx.x;
    const int wave = tid >> 6;
    const int lane = tid & 63;
    const int wr   = wave >> 2;            // 0..1 : M-half
    const int wc   = wave & 3;             // 0..3 : N-quarter
    const int r    = lane & 15;
    const int g    = lane >> 4;

    // XCD-aware block swizzle (nwg = 512, divisible by 8 -> bijective)
    const int nwg  = gridDim.x;
    const int orig = blockIdx.x;
    const int swz  = ((nwg & 7) == 0) ? ((orig & 7) * (nwg >> 3) + (orig >> 3))
                                      : orig;
    const int tN = N / BN;
    const int bn = swz % tN;
    const int bm = swz / tN;
    const int rowBase = bm * BM;
    const int colBase = bn * BN;

    // ---- staging geometry: thread t -> LDS byte t*16 of a 64-row slab ----
    const int srow = tid >> 3;                         // 0..63 within slab
    const int scol = (((tid & 7) ^ (srow & 7)) << 3);  // pre-swizzled elem col
    const unsigned short* aS = A + (size_t)(rowBase + srow) * K + scol;
    const unsigned short* bS = B + (size_t)(colBase + srow) * K + scol;
    const int dstOff = wave * 512;   // elements; lane*16B added by hardware

#define STG_A(P_, H_, S_, K0_) __builtin_amdgcn_global_load_lds(              \
    (gbl_void*)(aS + (size_t)((H_) * 128 + (S_) * 64) * K + (K0_)),           \
    (lds_void*)&lds[P_][0][H_][(S_) * 4096 + dstOff], 16, 0, 0)
#define STG_B(P_, H_, S_, K0_) __builtin_amdgcn_global_load_lds(              \
    (gbl_void*)(bS + (size_t)((H_) * 128 + (S_) * 64) * K + (K0_)),           \
    (lds_void*)&lds[P_][1][H_][(S_) * 4096 + dstOff], 16, 0, 0)

    // ---- fragment read geometry (mfma_f32_16x16x32: lane r+16g holds
    //      row r, k = 8g..8g+8 of the 32-wide k-step) ----
    const int sw    = r & 7;
    const int coff0 = ((g    ) ^ sw) << 3;   // k-step 0 chunk, swizzled
    const int coff1 = ((g + 4) ^ sw) << 3;   // k-step 1 chunk, swizzled
    const int aRowOff = r * 64;
    const int bRowOff = ((wc & 1) * 64 + r) * 64;

#define LDA(S_, MF_, C_) (*(const short8*)((S_) + (MF_) * 1024 + aRowOff + (C_)))
#define LDB(S_, NF_, C_) (*(const short8*)((S_) + (NF_) * 1024 + bRowOff + (C_)))
#define MM(ACC_, AV_, BV_) ACC_ = __builtin_amdgcn_mfma_f32_16x16x32_bf16(    \
    AV_, BV_, ACC_, 0, 0, 0)
#define SGB(M_, N_, S_) __builtin_amdgcn_sched_group_barrier(M_, N_, S_)

// 16 MFMA: k0 octet (A0_/A2_ x b*0) then k1 octet (A1_/A3_ x b*1)
#define OCTETS(MF0, A0_, A1_, A2_, A3_)                                       \
    MM(acc[MF0][0], A0_, b00); MM(acc[(MF0)+1][0], A2_, b00);                 \
    MM(acc[MF0][1], A0_, b10); MM(acc[(MF0)+1][1], A2_, b10);                 \
    MM(acc[MF0][2], A0_, b20); MM(acc[(MF0)+1][2], A2_, b20);                 \
    MM(acc[MF0][3], A0_, b30); MM(acc[(MF0)+1][3], A2_, b30);                 \
    MM(acc[MF0][0], A1_, b01); MM(acc[(MF0)+1][0], A3_, b01);                 \
    MM(acc[MF0][1], A1_, b11); MM(acc[(MF0)+1][1], A3_, b11);                 \
    MM(acc[MF0][2], A1_, b21); MM(acc[(MF0)+1][2], A3_, b21);                 \
    MM(acc[MF0][3], A1_, b31); MM(acc[(MF0)+1][3], A3_, b31);

// emission patterns: reads spread through the front of the MFMA window
#define SGB4                                                                  \
    SGB(0x8,2,0); SGB(0x100,1,0); SGB(0x8,2,0); SGB(0x100,1,0);               \
    SGB(0x8,2,0); SGB(0x100,1,0); SGB(0x8,2,0); SGB(0x100,1,0);               \
    SGB(0x8,8,0);
#define SGB8                                                                  \
    SGB(0x8,1,0); SGB(0x100,1,0); SGB(0x8,1,0); SGB(0x100,1,0);               \
    SGB(0x8,1,0); SGB(0x100,1,0); SGB(0x8,1,0); SGB(0x100,1,0);               \
    SGB(0x8,1,0); SGB(0x100,1,0); SGB(0x8,1,0); SGB(0x100,1,0);               \
    SGB(0x8,1,0); SGB(0x100,1,0); SGB(0x8,1,0); SGB(0x100,1,0);               \
    SGB(0x8,8,0);

#define CL_ENTRY                                                              \
    __builtin_amdgcn_s_barrier();                                             \
    asm volatile("s_waitcnt lgkmcnt(0)" ::: "memory");                        \
    __builtin_amdgcn_sched_barrier(0);                                        \
    __builtin_amdgcn_s_setprio(1);
#define CL_EXIT                                                               \
    __builtin_amdgcn_sched_barrier(0);                                        \
    __builtin_amdgcn_s_setprio(0);                                            \
    __builtin_amdgcn_s_barrier();

    f32x4 acc[8][4];
    #pragma unroll
    for (int i = 0; i < 8; ++i)
        #pragma unroll
        for (int j = 0; j < 4; ++j)
            #pragma unroll
            for (int e = 0; e < 4; ++e)
                acc[i][j][e] = 0.f;

    const int KT = K >> 6;   // K-tiles of 64

    // ---- prologue: tile0 fully (8 loads), tile1 all but A-slab0 (6) ----
    STG_B(0, 0, 0, 0); STG_B(0, 0, 1, 0); STG_B(0, 1, 0, 0); STG_B(0, 1, 1, 0);
    STG_A(0, 0, 0, 0); STG_A(0, 0, 1, 0); STG_A(0, 1, 0, 0); STG_A(0, 1, 1, 0);
    if (KT > 1) {
        STG_B(1, 0, 0, BK); STG_B(1, 0, 1, BK);
        STG_B(1, 1, 0, BK); STG_B(1, 1, 1, BK);
        STG_A(1, 0, 1, BK); STG_A(1, 1, 1, BK);
        asm volatile("s_waitcnt vmcnt(6)" ::: "memory");
    } else {
        asm volatile("s_waitcnt vmcnt(0)" ::: "memory");
    }
    __builtin_amdgcn_s_barrier();

    // ---- pre-loop reads: tile0 B-k0 + A-q3 (steady-state entry state) ----
    short8 b00, b10, b20, b30, b01, b11, b21, b31;
    short8 x0, x1, x2, x3, y0, y1, y2, y3, nb0, nb1, nb2, nb3;
    {
        const unsigned short* sA0 = &lds[0][0][wr][0];
        const unsigned short* sB0 = &lds[0][1][wc >> 1][0];
        b00 = LDB(sB0, 0, coff0); b10 = LDB(sB0, 1, coff0);
        b20 = LDB(sB0, 2, coff0); b30 = LDB(sB0, 3, coff0);
        x0 = LDA(sA0, 6, coff0);  x1 = LDA(sA0, 6, coff1);
        x2 = LDA(sA0, 7, coff0);  x3 = LDA(sA0, 7, coff1);
    }

    for (int kt = 0; kt < KT - 1; ++kt) {
        const int p  = kt & 1;
        const int pn = p ^ 1;
        const unsigned short* sA  = &lds[p][0][wr][0];
        const unsigned short* sB  = &lds[p][1][wc >> 1][0];
        const unsigned short* sAn = &lds[pn][0][wr][0];
        const unsigned short* sBn = &lds[pn][1][wc >> 1][0];
        const bool s2 = (kt + 2) < KT;
        const int kA = (kt + 1) << 6;
        const int kB = (kt + 2) << 6;

        // ---- phase 1 (q3): S1 + B-k1 pre-reads; cluster reads A-q2 ----
        STG_A(pn, 0, 0, kA); STG_A(pn, 1, 0, kA);
        b01 = LDB(sB, 0, coff1); b11 = LDB(sB, 1, coff1);
        b21 = LDB(sB, 2, coff1); b31 = LDB(sB, 3, coff1);
        CL_ENTRY
        OCTETS(6, x0, x1, x2, x3)
        y0 = LDA(sA, 4, coff0); y1 = LDA(sA, 4, coff1);
        y2 = LDA(sA, 5, coff0); y3 = LDA(sA, 5, coff1);
        SGB4
        CL_EXIT

        // ---- phase 2 (q2): cluster reads A-q1 ----
        if (s2) { STG_B(p, 0, 0, kB); STG_B(p, 0, 1, kB); }
        CL_ENTRY
        OCTETS(4, y0, y1, y2, y3)
        x0 = LDA(sA, 2, coff0); x1 = LDA(sA, 2, coff1);
        x2 = LDA(sA, 3, coff0); x3 = LDA(sA, 3, coff1);
        SGB4
        CL_EXIT

        // ---- phase 3 (q1): cluster reads A-q0 ----
        if (s2) { STG_B(p, 1, 0, kB); STG_B(p, 1, 1, kB); }
        CL_ENTRY
        OCTETS(2, x0, x1, x2, x3)
        y0 = LDA(sA, 0, coff0); y1 = LDA(sA, 0, coff1);
        y2 = LDA(sA, 1, coff0); y3 = LDA(sA, 1, coff1);
        SGB4
        CL_EXIT

        // ---- phase 4 (q0): counted wait; cluster reads next B-k0 + A-q3 ----
        if (s2) { STG_A(p, 0, 1, kB); STG_A(p, 1, 1, kB); }
        if (s2) asm volatile("s_waitcnt vmcnt(6)" ::: "memory");
        else    asm volatile("s_waitcnt vmcnt(0)" ::: "memory");
        CL_ENTRY
        OCTETS(0, y0, y1, y2, y3)
        nb0 = LDB(sBn, 0, coff0); nb1 = LDB(sBn, 1, coff0);
        nb2 = LDB(sBn, 2, coff0); nb3 = LDB(sBn, 3, coff0);
        x0 = LDA(sAn, 6, coff0);  x1 = LDA(sAn, 6, coff1);
        x2 = LDA(sAn, 7, coff0);  x3 = LDA(sAn, 7, coff1);
        SGB8
        CL_EXIT
        b00 = nb0; b10 = nb1; b20 = nb2; b30 = nb3;
    }

    // ---- tail tile (kt = KT-1): no staging, no next-tile reads ----
    {
        const int p = (KT - 1) & 1;
        const unsigned short* sA = &lds[p][0][wr][0];
        const unsigned short* sB = &lds[p][1][wc >> 1][0];

        b01 = LDB(sB, 0, coff1); b11 = LDB(sB, 1, coff1);
        b21 = LDB(sB, 2, coff1); b31 = LDB(sB, 3, coff1);
        CL_ENTRY
        OCTETS(6, x0, x1, x2, x3)
        y0 = LDA(sA, 4, coff0); y1 = LDA(sA, 4, coff1);
        y2 = LDA(sA, 5, coff0); y3 = LDA(sA, 5, coff1);
        SGB4
        CL_EXIT

        CL_ENTRY
        OCTETS(4, y0, y1, y2, y3)
        x0 = LDA(sA, 2, coff0); x1 = LDA(sA, 2, coff1);
        x2 = LDA(sA, 3, coff0); x3 = LDA(sA, 3, coff1);
        SGB4
        CL_EXIT

        CL_ENTRY
        OCTETS(2, x0, x1, x2, x3)
        y0 = LDA(sA, 0, coff0); y1 = LDA(sA, 0, coff1);
        y2 = LDA(sA, 1, coff0); y3 = LDA(sA, 1, coff1);
        SGB4
        CL_EXIT

        CL_ENTRY
        OCTETS(0, y0, y1, y2, y3)
        SGB(0x8, 16, 0);
        CL_EXIT
    }

    // ---- epilogue: C/D layout col = lane&15, row = (lane>>4)*4 + reg ----
    const int ecol  = colBase + wc * 64 + r;
    const int erow0 = rowBase + wr * 128 + g * 4;
    #pragma unroll
    for (int nf = 0; nf < 4; ++nf) {
        const int col = ecol + nf * 16;
        const float bv = bias[col];
        #pragma unroll
        for (int mf = 0; mf < 8; ++mf) {
            const int row0 = erow0 + mf * 16;
            #pragma unroll
            for (int j = 0; j < 4; ++j)
                C[(size_t)(row0 + j) * N + col] = acc[mf][nf][j] + bv;
        }
    }
#undef CL_ENTRY
#undef CL_EXIT
#undef SGB4
#undef SGB8
#undef OCTETS
#undef SGB
#undef MM
#undef LDA
#undef LDB
#undef STG_A
#undef STG_B
}

// ---------------------------------------------------------------------------
extern "C" void kernel_launch(void* const* d_in, const int* in_sizes, int n_in,
                              void* d_out, int out_size, void* d_ws, size_t ws_size,
                              hipStream_t stream) {
    const float* x = (const float*)d_in[0];   // [M,K]
    const float* W = (const float*)d_in[1];   // [N,K]
    const float* b = (const float*)d_in[2];   // [N]
    float* out = (float*)d_out;               // [M,N]

    const int N = in_sizes[2];                // 4096
    const int K = in_sizes[1] / N;            // 4096
    const int M = in_sizes[0] / K;            // 8192

    unsigned char* ws = (unsigned char*)d_ws;
    float* partials = (float*)ws;             // PREP_BLOCKS floats (4 KB)
    unsigned short* xb = (unsigned short*)(ws + 4096);
    unsigned short* wq = (unsigned short*)(ws + 4096 + (size_t)M * K * 2);

    prep_kernel<<<PREP_BLOCKS, 256, 0, stream>>>(W, x, xb, partials,
                                                 (N * K) / 4, (M * K) / 4);
    quantw_kernel<<<2048, 256, 0, stream>>>(W, partials, wq, (N * K) / 4);

    dim3 grid((N / BN) * (M / BM));           // 16*32 = 512, 1D for swizzle
    gemm_bt<<<grid, 512, 0, stream>>>(xb, wq, b, out, M, N, K);
}